// Round 1
// baseline (154.234 us; speedup 1.0000x reference)
//
#include <hip/hip_runtime.h>

#define FF 20
#define DD 16
#define EE 32          // H*D
#define NI 190         // F*(F-1)/2
#define BB 4096
#define FD 320         // F*D

// K1: W12[320][190] = senet_w1[320][320] @ senet_w2[320][190]
__global__ __launch_bounds__(192) void k_w12(const float* __restrict__ w1,
                                             const float* __restrict__ w2,
                                             float* __restrict__ W12) {
    __shared__ float srow[FD];
    int r = blockIdx.x;
    for (int j = threadIdx.x; j < FD; j += 192) srow[j] = w1[r * FD + j];
    __syncthreads();
    int c = threadIdx.x;
    if (c < NI) {
        float acc = 0.f;
        for (int k = 0; k < FD; ++k) acc += srow[k] * w2[k * NI + c];
        W12[r * NI + c] = acc;
    }
}

// K2: w[4096][190] = z[4096][320] @ W12[320][190], 8 b-rows per block
__global__ __launch_bounds__(192) void k_w(const float* __restrict__ z,
                                           const float* __restrict__ W12,
                                           float* __restrict__ wout) {
    __shared__ float sz[8 * FD];
    int b0 = blockIdx.x * 8;
    for (int j = threadIdx.x; j < 8 * FD; j += 192) sz[j] = z[b0 * FD + j];
    __syncthreads();
    int c = threadIdx.x;
    if (c < NI) {
        float acc[8] = {0.f, 0.f, 0.f, 0.f, 0.f, 0.f, 0.f, 0.f};
        for (int k = 0; k < FD; ++k) {
            float wv = W12[k * NI + c];
#pragma unroll
            for (int bb = 0; bb < 8; ++bb) acc[bb] += sz[bb * FD + k] * wv;
        }
#pragma unroll
        for (int bb = 0; bb < 8; ++bb) wout[(b0 + bb) * NI + c] = acc[bb];
    }
}

// K3: fused gather + transform + pair-weighted field reduction. One block per b.
__global__ __launch_bounds__(256) void k_main(const float* __restrict__ cb,   // [500000][16]
                                              const float* __restrict__ Wt,   // [32][16]
                                              const int* __restrict__ hidx,   // [2][B][NI]
                                              const int* __restrict__ iidx,   // [20][19]
                                              const float* __restrict__ wbuf, // [B][NI]
                                              float* __restrict__ out) {      // [B][20][16]
    __shared__ float s_rows[32 * 32];      // 32 pairs x concat(2 rows of 16)
    __shared__ float s_embw[NI * 16];      // emb * w per pair
    __shared__ int s_i0[NI], s_i1[NI];
    __shared__ float s_w[NI];
    __shared__ int s_pii[FF * (FF - 1)];

    int t = threadIdx.x;
    int b = blockIdx.x;

    for (int j = t; j < NI; j += 256) {
        s_i0[j] = hidx[b * NI + j];
        s_i1[j] = hidx[BB * NI + b * NI + j];
        s_w[j] = wbuf[b * NI + j];
    }
    for (int j = t; j < FF * (FF - 1); j += 256) s_pii[j] = iidx[j];

    int d = t & 15;
    float Wr[32];
#pragma unroll
    for (int k = 0; k < 32; ++k) Wr[k] = Wt[k * 16 + d];
    __syncthreads();

    const float4* cb4 = (const float4*)cb;
    int pp_st = t >> 3;        // 0..31 : pair slot for staging
    int q = t & 7;
    int h = q >> 2;            // which hash head
    int cq = q & 3;            // float4 chunk within row
    int pgrp = t >> 4;         // 0..15 : pair group for compute

    for (int base = 0; base < NI; base += 32) {
        int pair = base + pp_st;
        if (pair < NI) {
            int row = h ? s_i1[pair] : s_i0[pair];
            float4 v = cb4[row * 4 + cq];
            *(float4*)&s_rows[pp_st * 32 + h * 16 + cq * 4] = v;
        }
        __syncthreads();
#pragma unroll
        for (int pg = 0; pg < 2; ++pg) {
            int pp = pgrp + pg * 16;
            int pair2 = base + pp;
            if (pair2 < NI) {
                const float* r = &s_rows[pp * 32];
                float acc = 0.f;
#pragma unroll
                for (int k = 0; k < 32; ++k) acc += r[k] * Wr[k];
                s_embw[pair2 * 16 + d] = acc * s_w[pair2];
            }
        }
        __syncthreads();
    }

    // field reduction: out[b,i,d] = sum over 19 pairs containing field i
    for (int o = t; o < FD; o += 256) {
        int i = o >> 4;
        int dd = o & 15;
        float acc = 0.f;
#pragma unroll
        for (int s = 0; s < FF - 1; ++s) {
            int j = s_pii[i * (FF - 1) + s];
            acc += s_embw[j * 16 + dd];
        }
        out[b * FD + o] = acc;
    }
}

extern "C" void kernel_launch(void* const* d_in, const int* in_sizes, int n_in,
                              void* d_out, int out_size, void* d_ws, size_t ws_size,
                              hipStream_t stream) {
    const float* origin = (const float*)d_in[0];  // (B, F, D) = z
    const float* cb     = (const float*)d_in[1];  // (500000, 16)
    const float* Wt     = (const float*)d_in[2];  // (32, 16)
    const float* w1     = (const float*)d_in[3];  // (320, 320)
    const float* w2     = (const float*)d_in[4];  // (320, 190)
    const int*   hidx   = (const int*)d_in[5];    // (2, B, 190)
    const int*   iidx   = (const int*)d_in[6];    // (20, 19)
    float* out = (float*)d_out;

    float* W12  = (float*)d_ws;          // 320*190 floats
    float* wbuf = W12 + FD * NI;         // 4096*190 floats

    k_w12<<<FD, 192, 0, stream>>>(w1, w2, W12);
    k_w<<<BB / 8, 192, 0, stream>>>(origin, W12, wbuf);
    k_main<<<BB, 256, 0, stream>>>(cb, Wt, hidx, iidx, wbuf, out);
}